// Round 5
// baseline (5578.096 us; speedup 1.0000x reference)
//
#include <hip/hip_runtime.h>

typedef _Float16 half_t;
typedef _Float16 half2_t __attribute__((ext_vector_type(2)));
union pk_u { unsigned int u; half2_t h; };

#define EMB 64
#define NLAYERS 3
#define BSH2 8
#define BW2 256            // nodes per coarse bucket
#define NB2MAX 1024        // max bucket count (N<=262144)
#define GSPREAD 32         // gcount: one counter per 128-B line
#define CAP 10240          // tmp region per bucket (avg 8533 edges, +20%)
#define EGCAP 10496        // recs region per bucket: cnt + <=254 pad + align
#define P1_BATCH 4096
#define P1_TH 512
#define P1_EPT 8           // edges per thread in part_kernel (4096/512)
#define BINTH 512
#define GTH 512            // gather threads

// ---- NE-entry exclusive scan of in[] -> lstart[]; NE/2 threads active ----
template <int NE>
__device__ inline void scan_pow2(const int* __restrict__ in, int* __restrict__ lstart,
                                 int* __restrict__ pair) {
    const int H = NE / 2;
    int t = threadIdx.x;
    int a0 = 0, a1 = 0;
    if (t < H) { a0 = in[2 * t]; a1 = in[2 * t + 1]; pair[t] = a0 + a1; }
    __syncthreads();
    for (int off = 1; off < H; off <<= 1) {
        int u = 0;
        if (t < H && t >= off) u = pair[t - off];
        __syncthreads();
        if (t < H) pair[t] += u;
        __syncthreads();
    }
    if (t < H) {
        lstart[2 * t]     = pair[t] - a0 - a1;
        lstart[2 * t + 1] = pair[t] - a1;
    }
    __syncthreads();
}

// ---- pass 1: partition edges into 256-node buckets, LDS-sorted dense writes ----
// (unchanged from round 4 — record = (row<<8)|(col&255))
__global__ __launch_bounds__(512) void part_kernel(
        const int* __restrict__ row, const int* __restrict__ col,
        int* __restrict__ gcount, int* __restrict__ tmp, int E, int nb2) {
    __shared__ int hist[NB2MAX];
    __shared__ int lstart[NB2MAX];
    __shared__ int gbase[NB2MAX];
    __shared__ int pair[NB2MAX / 2];
    __shared__ int srec[P1_BATCH];
    __shared__ unsigned short sbuck[P1_BATCH];

    int base = blockIdx.x * P1_BATCH;
    int nE = min(P1_BATCH, E - base);

    for (int i = threadIdx.x; i < NB2MAX; i += P1_TH) hist[i] = 0;
    __syncthreads();

    int myc[P1_EPT];
    #pragma unroll
    for (int k = 0; k < P1_EPT; ++k) {
        int idx = base + (k << 9) + threadIdx.x;
        int c = (idx < E) ? col[idx] : -1;
        myc[k] = c;
        if (c >= 0) atomicAdd(&hist[c >> BSH2], 1);
    }
    __syncthreads();

    scan_pow2<NB2MAX>(hist, lstart, pair);

    for (int b = threadIdx.x; b < nb2; b += P1_TH) {
        int c = hist[b];
        int off = 0;
        if (c > 0) off = atomicAdd(&gcount[b * GSPREAD], c);
        gbase[b] = b * CAP + off - lstart[b];
    }
    __syncthreads();
    for (int b = threadIdx.x; b < NB2MAX; b += P1_TH) hist[b] = lstart[b];
    __syncthreads();

    #pragma unroll
    for (int k = 0; k < P1_EPT; ++k) {
        int idx = base + (k << 9) + threadIdx.x;
        if (idx < E) {
            int c = myc[k];
            int b = c >> BSH2;
            int r = row[idx];
            int pos = atomicAdd(&hist[b], 1);
            srec[pos] = (r << BSH2) | (c & (BW2 - 1));
            sbuck[pos] = (unsigned short)b;
        }
    }
    __syncthreads();

    for (int i = threadIdx.x; i < nE; i += P1_TH)
        tmp[gbase[sbuck[i]] + i] = srec[i];
}

// ---- pass 2: per bucket: dst-degree hist (-> dis), then sort records by
//      (half, src>>9) so the gather walks sources in ascending order.
//      Each 128-node half padded to x128 recs with sentinel (src=N zero row).
//      Also fused s0 init (s0 = fp16(dis*x)). ----
__global__ __launch_bounds__(512) void bin_kernel(
        const int* __restrict__ tmp, const int* __restrict__ gcount,
        int* __restrict__ recs, int2* __restrict__ hdesc, float* __restrict__ dis,
        const float4* __restrict__ uev, const float4* __restrict__ mev,
        uint2* __restrict__ s0v,
        int n_users, int N) {
    __shared__ int histd[BW2];
    __shared__ int hist2[1024];
    __shared__ int lstart[1024];
    __shared__ int pair[512];
    __shared__ float sdis[BW2];
    __shared__ int sc[4];
    int b = blockIdx.x;
    int cnt = gcount[b * GSPREAD];
    int rbase = b * CAP;
    int ebase = b * EGCAP;
    int c0 = b << BSH2;
    int nc = min(BW2, N - c0);

    for (int i = threadIdx.x; i < BW2; i += BINTH) histd[i] = 0;
    for (int i = threadIdx.x; i < 1024; i += BINTH) hist2[i] = 0;
    __syncthreads();

    // one read pass: dst-degree + (half, src-granule) histogram
    for (int i = threadIdx.x; i < cnt; i += BINTH) {
        int rec = tmp[rbase + i];
        atomicAdd(&histd[rec & (BW2 - 1)], 1);
        int key = (((rec >> 7) & 1) << 9) + (rec >> 17);   // half*512 + (src>>9)
        atomicAdd(&hist2[key], 1);
    }
    __syncthreads();

    scan_pow2<1024>(hist2, lstart, pair);

    if (threadIdx.x == 0) {
        int lenA = lstart[512];
        int padA = ((lenA + 127) & ~127) - lenA;
        int total = lstart[1023] + hist2[1023];
        int lenB = total - lenA;
        int padB = ((lenB + 127) & ~127) - lenB;
        sc[0] = lenA; sc[1] = padA; sc[2] = lenB; sc[3] = padB;
        hdesc[b * 2 + 0] = make_int2(ebase, lenA + padA);
        hdesc[b * 2 + 1] = make_int2(ebase + lenA + padA, lenB + padB);
    }

    // per-node dis
    for (int c = threadIdx.x; c < nc; c += BINTH) {
        int d = histd[c];
        float dn = (d > 0) ? rsqrtf((float)d) : 0.0f;
        dis[c0 + c] = dn;
        sdis[c] = dn;
    }
    __syncthreads();
    int lenA = sc[0], padA = sc[1], lenB = sc[2], padB = sc[3];

    // cursors (half B shifted by padA so each half starts x128-aligned)
    for (int k = threadIdx.x; k < 1024; k += BINTH)
        hist2[k] = lstart[k] + ((k >= 512) ? padA : 0);
    __syncthreads();

    // scatter records in (half, src-granule) order
    for (int i = threadIdx.x; i < cnt; i += BINTH) {
        int rec = tmp[rbase + i];
        int key = (((rec >> 7) & 1) << 9) + (rec >> 17);
        int pos = atomicAdd(&hist2[key], 1);
        recs[ebase + pos] = rec;
    }

    // sentinel pads (src=N zero row, dst=local 0 of the half: adds 0, harmless)
    int sentA = (N << 8);
    int sentB = (N << 8) | 128;
    for (int i = threadIdx.x; i < padA; i += BINTH) recs[ebase + lenA + i] = sentA;
    for (int i = threadIdx.x; i < padB; i += BINTH)
        recs[ebase + lenA + padA + lenB + i] = sentB;

    // fused s0 init: s0 = fp16(dis*x)
    for (int i = threadIdx.x; i < nc * 16; i += BINTH) {
        int loc = i >> 4;
        int node = c0 + loc;
        int q = i & 15;
        const float4* src = (node < n_users) ? (uev + (long long)node * 16)
                                             : (mev + (long long)(node - n_users) * 16);
        float4 v = src[q];
        float dn = sdis[loc];
        pk_u w0, w1;
        w0.h[0] = (half_t)(v.x * dn); w0.h[1] = (half_t)(v.y * dn);
        w1.h[0] = (half_t)(v.z * dn); w1.h[1] = (half_t)(v.w * dn);
        s0v[(long long)node * 16 + q] = make_uint2(w0.u, w1.u);
    }
}

// ---------------- propagate: src-ordered walk + LDS fp32 accumulators --------
// Block = 128 dst nodes. Edges sorted by src (512-row granules): all co-resident
// blocks walk the table in the same ascending order -> each table line fetched
// ~once per XCD (L2-resident window) instead of ~2x (thrash).
// Per iter: lane l handles rec slot (l>>3), dims (l&7)*8.. ; 2 recs per lane.
// acc stride 65 floats (65%32==1) -> banks spread by dst.
// LAYER 1: writes s1 + u1=fp16(a1); LAYER 2: s2 + u2; LAYER 3: out=(x+u1+u2+a3)/4
template <int LAYER>
__global__ __launch_bounds__(512) void gather_kernel(
        const int* __restrict__ recs, const int2* __restrict__ hdesc,
        const float* __restrict__ dis, const uint4* __restrict__ tab,
        uint2* __restrict__ sOut, uint2* __restrict__ uOut,
        const uint2* __restrict__ u1, const uint2* __restrict__ u2,
        const float4* __restrict__ uev, const float4* __restrict__ mev,
        float4* __restrict__ outv, int n_users, int N) {
    __shared__ float sacc[128 * 65];
    __shared__ float sdis[128];
    int g = blockIdx.x;
    int2 hd = hdesc[g];
    int c0 = ((g >> 1) << BSH2) + ((g & 1) << 7);

    for (int i = threadIdx.x; i < 128 * 65; i += GTH) sacc[i] = 0.0f;
    if (threadIdx.x < 128) {
        int node = c0 + threadIdx.x;
        sdis[threadIdx.x] = (node < N) ? dis[node] : 0.0f;
    }
    __syncthreads();

    int eslot = threadIdx.x >> 3;
    int s = threadIdx.x & 7;
    const char* tb = (const char*)tab;
    unsigned pb = (unsigned)s << 4;

    for (int i = 0; i < hd.y; i += 128) {
        int rec0 = recs[hd.x + i + eslot];
        int rec1 = recs[hd.x + i + 64 + eslot];
        uint4 v0 = *(const uint4*)(tb + (((unsigned)rec0 >> 8) << 7) + pb);
        uint4 v1 = *(const uint4*)(tb + (((unsigned)rec1 >> 8) << 7) + pb);
        int d0 = (rec0 & 127) * 65 + s * 8;
        int d1 = (rec1 & 127) * 65 + s * 8;
        pk_u t;
        t.u = v0.x; atomicAdd(&sacc[d0 + 0], (float)t.h[0]); atomicAdd(&sacc[d0 + 1], (float)t.h[1]);
        t.u = v0.y; atomicAdd(&sacc[d0 + 2], (float)t.h[0]); atomicAdd(&sacc[d0 + 3], (float)t.h[1]);
        t.u = v0.z; atomicAdd(&sacc[d0 + 4], (float)t.h[0]); atomicAdd(&sacc[d0 + 5], (float)t.h[1]);
        t.u = v0.w; atomicAdd(&sacc[d0 + 6], (float)t.h[0]); atomicAdd(&sacc[d0 + 7], (float)t.h[1]);
        t.u = v1.x; atomicAdd(&sacc[d1 + 0], (float)t.h[0]); atomicAdd(&sacc[d1 + 1], (float)t.h[1]);
        t.u = v1.y; atomicAdd(&sacc[d1 + 2], (float)t.h[0]); atomicAdd(&sacc[d1 + 3], (float)t.h[1]);
        t.u = v1.z; atomicAdd(&sacc[d1 + 4], (float)t.h[0]); atomicAdd(&sacc[d1 + 5], (float)t.h[1]);
        t.u = v1.w; atomicAdd(&sacc[d1 + 6], (float)t.h[0]); atomicAdd(&sacc[d1 + 7], (float)t.h[1]);
    }
    __syncthreads();

    if (LAYER < 3) {
        for (int idx = threadIdx.x; idx < 128 * 16; idx += GTH) {
            int loc = idx >> 4, q = idx & 15;
            int node = c0 + loc;
            if (node >= N) continue;
            float dc = sdis[loc];
            const float* ap = &sacc[loc * 65 + q * 4];
            float g0 = dc * ap[0], g1 = dc * ap[1], g2 = dc * ap[2], g3 = dc * ap[3];
            pk_u w0, w1, uw0, uw1;
            w0.h[0] = (half_t)(dc * g0); w0.h[1] = (half_t)(dc * g1);
            w1.h[0] = (half_t)(dc * g2); w1.h[1] = (half_t)(dc * g3);
            uw0.h[0] = (half_t)g0; uw0.h[1] = (half_t)g1;
            uw1.h[0] = (half_t)g2; uw1.h[1] = (half_t)g3;
            long long o16 = (long long)node * 16 + q;
            sOut[o16] = make_uint2(w0.u, w1.u);
            long long uo = (LAYER == 1) ? o16 : ((long long)node * 32 + q);
            uOut[uo] = make_uint2(uw0.u, uw1.u);
        }
    } else {
        // compute all results first (u2 aliases out rows) then barrier then store
        float4 res[4];
        long long oo[4];
        #pragma unroll
        for (int k = 0; k < 4; ++k) {
            int idx = threadIdx.x + k * GTH;
            int loc = idx >> 4, q = idx & 15;
            int node = c0 + loc;
            float4 r = make_float4(0.f, 0.f, 0.f, 0.f);
            long long o16 = (long long)node * 16 + q;
            if (node < N) {
                float dc = sdis[loc];
                const float* ap = &sacc[loc * 65 + q * 4];
                float g0 = dc * ap[0], g1 = dc * ap[1], g2 = dc * ap[2], g3 = dc * ap[3];
                const float4* src = (node < n_users) ? (uev + (long long)node * 16)
                                                     : (mev + (long long)(node - n_users) * 16);
                float4 xv = src[q];
                uint2 ua = u1[o16];
                uint2 ub = u2[(long long)node * 32 + q];
                pk_u pa, pb2, pc, pd;
                pa.u = ua.x; pb2.u = ua.y; pc.u = ub.x; pd.u = ub.y;
                r.x = (xv.x + (float)pa.h[0]  + (float)pc.h[0] + g0) * 0.25f;
                r.y = (xv.y + (float)pa.h[1]  + (float)pc.h[1] + g1) * 0.25f;
                r.z = (xv.z + (float)pb2.h[0] + (float)pd.h[0] + g2) * 0.25f;
                r.w = (xv.w + (float)pb2.h[1] + (float)pd.h[1] + g3) * 0.25f;
                oo[k] = o16;
            } else {
                oo[k] = -1;
            }
            res[k] = r;
        }
        __syncthreads();
        #pragma unroll
        for (int k = 0; k < 4; ++k)
            if (oo[k] >= 0) outv[oo[k]] = res[k];
    }
}

extern "C" void kernel_launch(void* const* d_in, const int* in_sizes, int n_in,
                              void* d_out, int out_size, void* d_ws, size_t ws_size,
                              hipStream_t stream) {
    const int*   edge = (const int*)d_in[0];    // [2, E]: row then col
    const float* ue   = (const float*)d_in[2];
    const float* me   = (const float*)d_in[3];
    float*       out  = (float*)d_out;

    const int E        = in_sizes[0] / 2;
    const int n_users  = in_sizes[2] / EMB;
    const int n_movies = in_sizes[3] / EMB;
    const int N        = n_users + n_movies;
    const int* row = edge;
    const int* col = edge + E;
    const int nb2 = (N + BW2 - 1) >> BSH2;      // 586 coarse buckets

    // workspace layout
    char* ws = (char*)d_ws;
    auto align_up = [](size_t v) { return (v + 255) & ~(size_t)255; };
    int*    gcount = (int*)ws;    ws += align_up((size_t)NB2MAX * GSPREAD * sizeof(int));
    int2*   hdesc  = (int2*)ws;   ws += align_up((size_t)NB2MAX * 2 * sizeof(int2));
    float*  dis    = (float*)ws;  ws += align_up((size_t)N * sizeof(float));
    int*    tmp    = (int*)ws;    ws += align_up((size_t)nb2 * CAP * sizeof(int));
    int*    recs   = (int*)ws;    ws += align_up((size_t)nb2 * EGCAP * sizeof(int));
    half_t* sA     = (half_t*)ws; ws += align_up((size_t)(N + 1) * EMB * sizeof(half_t));
    half_t* sB     = (half_t*)ws; ws += align_up((size_t)(N + 1) * EMB * sizeof(half_t));
    // u1 = fp16(a1), stride-16 rows: aliases tmp (dead after bin_kernel; 19.2<=24MB)
    uint2* u1 = (uint2*)tmp;
    // u2 = fp16(a2), stride-32 rows: lives in the (unwritten) out buffer
    uint2* u2 = (uint2*)out;

    hipMemsetAsync(gcount, 0, (size_t)NB2MAX * GSPREAD * sizeof(int), stream);
    hipMemsetAsync(sA + (size_t)N * EMB, 0, EMB * sizeof(half_t), stream);  // zero row
    hipMemsetAsync(sB + (size_t)N * EMB, 0, EMB * sizeof(half_t), stream);  // zero row
    part_kernel<<<(E + P1_BATCH - 1) / P1_BATCH, P1_TH, 0, stream>>>(
        row, col, gcount, tmp, E, nb2);
    bin_kernel<<<nb2, BINTH, 0, stream>>>(
        tmp, gcount, recs, hdesc, dis,
        (const float4*)ue, (const float4*)me, (uint2*)sA,
        n_users, N);

    // 3 propagation layers: src-ordered LDS-accumulate gather
    const int gblocks = 2 * nb2;     // one block per 128-node half-bucket
    gather_kernel<1><<<gblocks, GTH, 0, stream>>>(
        recs, hdesc, dis, (const uint4*)sA, (uint2*)sB, u1,
        nullptr, nullptr, nullptr, nullptr, nullptr, n_users, N);
    gather_kernel<2><<<gblocks, GTH, 0, stream>>>(
        recs, hdesc, dis, (const uint4*)sB, (uint2*)sA, u2,
        nullptr, nullptr, nullptr, nullptr, nullptr, n_users, N);
    gather_kernel<3><<<gblocks, GTH, 0, stream>>>(
        recs, hdesc, dis, (const uint4*)sA, nullptr, nullptr,
        (const uint2*)u1, (const uint2*)u2,
        (const float4*)ue, (const float4*)me, (float4*)out, n_users, N);
}

// Round 6
// 472.086 us; speedup vs baseline: 11.8159x; 11.8159x over previous
//
#include <hip/hip_runtime.h>

typedef _Float16 half_t;
typedef _Float16 half2_t __attribute__((ext_vector_type(2)));
union pk_u { unsigned int u; half2_t h; };

#define EMB 64
#define NLAYERS 3
#define BSH2 8
#define BW2 256            // nodes per coarse bucket
#define NB2MAX 1024        // max bucket count (N<=262144)
#define GSPREAD 32         // gcount: one counter per 128-B line
#define CAP 10240          // tmp region per bucket (avg 8533 edges, +20%)
#define EGCAP 16384        // eg region per bucket: 32-padded lists (avg ~12.6K) + slack
#define P1_BATCH 4096
#define P1_TH 512
#define P1_EPT 8           // edges per thread in part_kernel (4096/512)
#define BINTH 512

// ---- NE-entry exclusive scan of in[] -> lstart[]; NE/2 threads active ----
template <int NE>
__device__ inline void scan_pow2(const int* __restrict__ in, int* __restrict__ lstart,
                                 int* __restrict__ pair) {
    const int H = NE / 2;
    int t = threadIdx.x;
    int a0 = 0, a1 = 0;
    if (t < H) { a0 = in[2 * t]; a1 = in[2 * t + 1]; pair[t] = a0 + a1; }
    __syncthreads();
    for (int off = 1; off < H; off <<= 1) {
        int u = 0;
        if (t < H && t >= off) u = pair[t - off];
        __syncthreads();
        if (t < H) pair[t] += u;
        __syncthreads();
    }
    if (t < H) {
        lstart[2 * t]     = pair[t] - a0 - a1;
        lstart[2 * t + 1] = pair[t] - a1;
    }
    __syncthreads();
}

// ---- pass 1: partition edges into 256-node buckets, LDS-sorted dense writes ----
// record = (row<<8)|(col&255)
__global__ __launch_bounds__(512) void part_kernel(
        const int* __restrict__ row, const int* __restrict__ col,
        int* __restrict__ gcount, int* __restrict__ tmp, int E, int nb2) {
    __shared__ int hist[NB2MAX];
    __shared__ int lstart[NB2MAX];
    __shared__ int gbase[NB2MAX];
    __shared__ int pair[NB2MAX / 2];
    __shared__ int srec[P1_BATCH];
    __shared__ unsigned short sbuck[P1_BATCH];

    int base = blockIdx.x * P1_BATCH;
    int nE = min(P1_BATCH, E - base);

    for (int i = threadIdx.x; i < NB2MAX; i += P1_TH) hist[i] = 0;
    __syncthreads();

    int myc[P1_EPT];
    #pragma unroll
    for (int k = 0; k < P1_EPT; ++k) {
        int idx = base + (k << 9) + threadIdx.x;
        int c = (idx < E) ? col[idx] : -1;
        myc[k] = c;
        if (c >= 0) atomicAdd(&hist[c >> BSH2], 1);
    }
    __syncthreads();

    scan_pow2<NB2MAX>(hist, lstart, pair);

    for (int b = threadIdx.x; b < nb2; b += P1_TH) {
        int c = hist[b];
        int off = 0;
        if (c > 0) off = atomicAdd(&gcount[b * GSPREAD], c);
        gbase[b] = b * CAP + off - lstart[b];
    }
    __syncthreads();
    for (int b = threadIdx.x; b < NB2MAX; b += P1_TH) hist[b] = lstart[b];
    __syncthreads();

    #pragma unroll
    for (int k = 0; k < P1_EPT; ++k) {
        int idx = base + (k << 9) + threadIdx.x;
        if (idx < E) {
            int c = myc[k];
            int b = c >> BSH2;
            int r = row[idx];
            int pos = atomicAdd(&hist[b], 1);
            srec[pos] = (r << BSH2) | (c & (BW2 - 1));
            sbuck[pos] = (unsigned short)b;
        }
    }
    __syncthreads();

    for (int i = threadIdx.x; i < nE; i += P1_TH)
        tmp[gbase[sbuck[i]] + i] = srec[i];
}

// ---- pass 2: one block per 256-node bucket. SINGLE global read of tmp:
//      stage records into LDS (40 KB) while building the dst histogram, then
//      scan + scatter from LDS into the ZERO-PADDED eg (x32 lists, sentinel
//      row N, byte offsets <<7). Fused s0 init (s0 = fp16(dis*x)) and the
//      sentinel zero rows for both fp16 tables (block 0). ----
__global__ __launch_bounds__(512) void bin_kernel(
        const int* __restrict__ tmp, const int* __restrict__ gcount,
        int* __restrict__ eg, int2* __restrict__ sd, float* __restrict__ dis,
        const float4* __restrict__ uev, const float4* __restrict__ mev,
        uint2* __restrict__ s0v, uint2* __restrict__ sbz,
        int n_users, int N) {
    __shared__ int srec[CAP];        // 40 KB staged records
    __shared__ int hist[BW2];
    __shared__ int padh[BW2];
    __shared__ int lstart[BW2];
    __shared__ int pair[BW2 / 2];
    __shared__ float sdis[BW2];
    int b = blockIdx.x;
    int cnt = gcount[b * GSPREAD];
    int rbase = b * CAP;             // tmp region
    int ebase = b * EGCAP;           // eg region (padded)
    int c0 = b << BSH2;
    int nc = min(BW2, N - c0);
    int sent = N << 7;               // sentinel: byte offset of zero row

    for (int i = threadIdx.x; i < BW2; i += BINTH) hist[i] = 0;
    __syncthreads();

    // ONE global pass: stage to LDS + dst histogram
    for (int i = threadIdx.x; i < cnt; i += BINTH) {
        int rec = tmp[rbase + i];
        srec[i] = rec;
        atomicAdd(&hist[rec & (BW2 - 1)], 1);
    }
    __syncthreads();

    // padded counts (multiple of 32)
    for (int c = threadIdx.x; c < BW2; c += BINTH)
        padh[c] = (hist[c] + 31) & ~31;
    __syncthreads();

    scan_pow2<BW2>(padh, lstart, pair);   // prefix over padded counts

    // per-node metadata: sd = (padded start, padded count), dis = rsqrt(true deg)
    for (int c = threadIdx.x; c < nc; c += BINTH) {
        int d = hist[c];
        float dn = (d > 0) ? rsqrtf((float)d) : 0.0f;
        sd[c0 + c] = make_int2(ebase + lstart[c], padh[c]);
        dis[c0 + c] = dn;
        sdis[c] = dn;
    }
    __syncthreads();
    for (int i = threadIdx.x; i < BW2; i += BINTH) hist[i] = lstart[i];  // cursors
    __syncthreads();

    // scatter src byte-offsets (src*128) from LDS
    for (int i = threadIdx.x; i < cnt; i += BINTH) {
        int v = srec[i];
        int pos = atomicAdd(&hist[v & (BW2 - 1)], 1);
        eg[ebase + pos] = (v >> BSH2) << 7;
    }
    __syncthreads();

    // pad-fill: cursor = lstart+deg; fill up to lstart+padh (<32/node) with sentinel
    for (int i = threadIdx.x; i < BW2 * 32; i += BINTH) {
        int c = i >> 5;
        int o = i & 31;
        int st = hist[c];
        int en = lstart[c] + padh[c];
        if (st + o < en) eg[ebase + st + o] = sent;
    }
    // 64 slack slots after the last list (covers the gather's 2-deep prefetch)
    int tot = lstart[BW2 - 1] + padh[BW2 - 1];
    if (threadIdx.x < 64) eg[ebase + tot + threadIdx.x] = sent;

    // sentinel zero rows for both fp16 tables (replaces two memsets)
    if (b == 0 && threadIdx.x < 32) {
        int q = threadIdx.x & 15;
        uint2 z = make_uint2(0u, 0u);
        if (threadIdx.x < 16) s0v[(long long)N * 16 + q] = z;
        else                  sbz[(long long)N * 16 + q] = z;
    }

    // fused s0 init for this bucket's nodes: s0 = fp16(dis*x)
    for (int i = threadIdx.x; i < nc * 16; i += BINTH) {
        int loc = i >> 4;
        int node = c0 + loc;
        int q = i & 15;
        const float4* src = (node < n_users) ? (uev + (long long)node * 16)
                                             : (mev + (long long)(node - n_users) * 16);
        float4 v = src[q];
        float dn = sdis[loc];
        pk_u w0, w1;
        w0.h[0] = (half_t)(v.x * dn); w0.h[1] = (half_t)(v.y * dn);
        w1.h[0] = (half_t)(v.z * dn); w1.h[1] = (half_t)(v.w * dn);
        s0v[(long long)node * 16 + q] = make_uint2(w0.u, w1.u);
    }
}

// ---------------- pull propagate: 8 lanes/row (dwordx4), 8 edge phases --------
// (round-4 proven version: 94.1 us/layer = traffic wall)
// lane l: p=l&7 owns dims 8p..8p+7 (one uint4/row); h=l>>3 owns edge (j+8k+h).
// Lists zero-padded to x32 (sentinel row N = zeros): branch-free, predicate-free.
// 2-deep eg prefetch (safe via 64 sentinel slack slots per bucket).
// LAYER 1: reads s0, writes s1 + u1=fp16(a1) (u1 stride-16 rows, aliases tmp)
// LAYER 2: reads s1, writes s2 + u2=fp16(a2) (u2 stride-32 rows, lives in out)
// LAYER 3: reads s2 + x + u1 + u2, writes out = (x+u1+u2+a3)/4
template <int LAYER>
__global__ __launch_bounds__(256) void gather_kernel(
        const int* __restrict__ eg, const int2* __restrict__ sd,
        const float* __restrict__ dis,
        const uint4* __restrict__ tab, uint2* __restrict__ sOut,
        uint2* __restrict__ uOut,
        const uint2* __restrict__ u1, const uint2* __restrict__ u2,
        const float4* __restrict__ uev, const float4* __restrict__ mev,
        float4* __restrict__ outv, int n_users, int N) {
    int wave = blockIdx.x * (blockDim.x >> 6) + (threadIdx.x >> 6);
    if (wave >= N) return;
    int l = threadIdx.x & 63;
    int p = l & 7;
    int h = l >> 3;
    unsigned pb = (unsigned)p << 4;          // byte offset of this lane's uint4
    const char* tb = (const char*)tab;

    int2 se = sd[wave];
    int j = se.x;
    int e = se.x + se.y;                     // se.y = padded count (x32)
    pk_u a0, a1, a2, a3;
    a0.u = 0; a1.u = 0; a2.u = 0; a3.u = 0;

    if (j < e) {
        int r0 = eg[j + h];
        int r1 = eg[j + 8 + h];
        int r2 = eg[j + 16 + h];
        int r3 = eg[j + 24 + h];
        for (; j < e; j += 32) {
            int n0 = eg[j + 32 + h];         // prefetch next chunk (slack-safe)
            int n1 = eg[j + 40 + h];
            int n2 = eg[j + 48 + h];
            int n3 = eg[j + 56 + h];
            // eg stores src*128 (byte offset); + pb = this lane's uint4
            uint4 v0 = *(const uint4*)(tb + ((unsigned)r0 + pb));
            uint4 v1 = *(const uint4*)(tb + ((unsigned)r1 + pb));
            uint4 v2 = *(const uint4*)(tb + ((unsigned)r2 + pb));
            uint4 v3 = *(const uint4*)(tb + ((unsigned)r3 + pb));
            pk_u t;
            t.u = v0.x; a0.h += t.h; t.u = v0.y; a1.h += t.h;
            t.u = v0.z; a2.h += t.h; t.u = v0.w; a3.h += t.h;
            t.u = v1.x; a0.h += t.h; t.u = v1.y; a1.h += t.h;
            t.u = v1.z; a2.h += t.h; t.u = v1.w; a3.h += t.h;
            t.u = v2.x; a0.h += t.h; t.u = v2.y; a1.h += t.h;
            t.u = v2.z; a2.h += t.h; t.u = v2.w; a3.h += t.h;
            t.u = v3.x; a0.h += t.h; t.u = v3.y; a1.h += t.h;
            t.u = v3.z; a2.h += t.h; t.u = v3.w; a3.h += t.h;
            r0 = n0; r1 = n1; r2 = n2; r3 = n3;
        }
    }

    // reduce across the 8 edge-phases (packed); all lanes end with full sums
    #pragma unroll
    for (int m = 8; m <= 32; m <<= 1) {
        pk_u t;
        t.u = (unsigned int)__shfl_xor((int)a0.u, m); a0.h += t.h;
        t.u = (unsigned int)__shfl_xor((int)a1.u, m); a1.h += t.h;
        t.u = (unsigned int)__shfl_xor((int)a2.u, m); a2.h += t.h;
        t.u = (unsigned int)__shfl_xor((int)a3.u, m); a3.h += t.h;
    }

    if (h < 2) {                             // 16 lanes handle the 64-dim row
        pk_u x0 = h ? a2 : a0;
        pk_u x1 = h ? a3 : a1;
        float dc = dis[wave];
        float g0 = dc * (float)x0.h[0];
        float g1 = dc * (float)x0.h[1];
        float g2 = dc * (float)x1.h[0];
        float g3 = dc * (float)x1.h[1];
        int q = p * 2 + h;
        long long o16 = (long long)wave * 16 + q;
        if (LAYER < 3) {
            pk_u w0, w1, uw0, uw1;
            w0.h[0] = (half_t)(dc * g0); w0.h[1] = (half_t)(dc * g1);
            w1.h[0] = (half_t)(dc * g2); w1.h[1] = (half_t)(dc * g3);
            uw0.h[0] = (half_t)g0; uw0.h[1] = (half_t)g1;
            uw1.h[0] = (half_t)g2; uw1.h[1] = (half_t)g3;
            sOut[o16] = make_uint2(w0.u, w1.u);
            long long uo = (LAYER == 1) ? o16 : ((long long)wave * 32 + q);
            uOut[uo] = make_uint2(uw0.u, uw1.u);
        } else {
            const float4* src = (wave < n_users) ? (uev + (long long)wave * 16)
                                                 : (mev + (long long)(wave - n_users) * 16);
            float4 xv = src[q];
            uint2 ua2 = u1[o16];
            uint2 ub2 = u2[(long long)wave * 32 + q];
            pk_u pa, pb2, pc, pd;
            pa.u = ua2.x; pb2.u = ua2.y; pc.u = ub2.x; pd.u = ub2.y;
            float4 r;
            r.x = (xv.x + (float)pa.h[0]  + (float)pc.h[0] + g0) * 0.25f;
            r.y = (xv.y + (float)pa.h[1]  + (float)pc.h[1] + g1) * 0.25f;
            r.z = (xv.z + (float)pb2.h[0] + (float)pd.h[0] + g2) * 0.25f;
            r.w = (xv.w + (float)pb2.h[1] + (float)pd.h[1] + g3) * 0.25f;
            outv[o16] = r;                   // same-row in-place over u2: load-before-store
        }
    }
}

extern "C" void kernel_launch(void* const* d_in, const int* in_sizes, int n_in,
                              void* d_out, int out_size, void* d_ws, size_t ws_size,
                              hipStream_t stream) {
    const int*   edge = (const int*)d_in[0];    // [2, E]: row then col
    const float* ue   = (const float*)d_in[2];
    const float* me   = (const float*)d_in[3];
    float*       out  = (float*)d_out;

    const int E        = in_sizes[0] / 2;
    const int n_users  = in_sizes[2] / EMB;
    const int n_movies = in_sizes[3] / EMB;
    const int N        = n_users + n_movies;
    const int* row = edge;
    const int* col = edge + E;
    const int nb2 = (N + BW2 - 1) >> BSH2;      // 586 coarse buckets

    // workspace layout
    char* ws = (char*)d_ws;
    auto align_up = [](size_t v) { return (v + 255) & ~(size_t)255; };
    int*    gcount = (int*)ws;    ws += align_up((size_t)NB2MAX * GSPREAD * sizeof(int));
    int2*   sd     = (int2*)ws;   ws += align_up((size_t)N * sizeof(int2));
    float*  dis    = (float*)ws;  ws += align_up((size_t)N * sizeof(float));
    int*    tmp    = (int*)ws;    ws += align_up((size_t)nb2 * CAP * sizeof(int));
    int*    eg     = (int*)ws;    ws += align_up((size_t)nb2 * EGCAP * sizeof(int));
    half_t* sA     = (half_t*)ws; ws += align_up((size_t)(N + 1) * EMB * sizeof(half_t));
    half_t* sB     = (half_t*)ws; ws += align_up((size_t)(N + 1) * EMB * sizeof(half_t));
    // u1 = fp16(a1), stride-16 rows: aliases tmp (dead after bin_kernel; 19.2<=24MB)
    uint2* u1 = (uint2*)tmp;
    // u2 = fp16(a2), stride-32 rows: lives in the (unwritten) out buffer
    uint2* u2 = (uint2*)out;

    // two-pass counting sort -> padded CSR (deg/dis/s0/zero-rows fused in pass 2)
    hipMemsetAsync(gcount, 0, (size_t)NB2MAX * GSPREAD * sizeof(int), stream);
    part_kernel<<<(E + P1_BATCH - 1) / P1_BATCH, P1_TH, 0, stream>>>(
        row, col, gcount, tmp, E, nb2);
    bin_kernel<<<nb2, BINTH, 0, stream>>>(
        tmp, gcount, eg, sd, dis,
        (const float4*)ue, (const float4*)me, (uint2*)sA, (uint2*)sB,
        n_users, N);

    // 3 propagation layers (atomic-free pull, packed fp16, no out RMW)
    const int waves_per_block = 4;   // 256 threads
    const int gblocks = (N + waves_per_block - 1) / waves_per_block;
    gather_kernel<1><<<gblocks, 256, 0, stream>>>(
        eg, sd, dis, (const uint4*)sA, (uint2*)sB, u1,
        nullptr, nullptr, nullptr, nullptr, nullptr, n_users, N);
    gather_kernel<2><<<gblocks, 256, 0, stream>>>(
        eg, sd, dis, (const uint4*)sB, (uint2*)sA, u2,
        nullptr, nullptr, nullptr, nullptr, nullptr, n_users, N);
    gather_kernel<3><<<gblocks, 256, 0, stream>>>(
        eg, sd, dis, (const uint4*)sA, nullptr, nullptr,
        (const uint2*)u1, (const uint2*)u2,
        (const float4*)ue, (const float4*)me, (float4*)out, n_users, N);
}